// Round 1
// baseline (295.516 us; speedup 1.0000x reference)
//
#include <hip/hip_runtime.h>

typedef __bf16 bf16_t;
typedef __bf16 bf16x8 __attribute__((ext_vector_type(8)));
typedef float f32x4 __attribute__((ext_vector_type(4)));
typedef unsigned int u32x4 __attribute__((ext_vector_type(4)));

#define KDIM 512
#define NDIM 512
#define BM 128
#define BN 128
#define BK 32
#define WSTRIDE 40  // padded bf16 row stride for weight tiles (80 B -> 2-way banks, free)

// async 16B global->LDS. LDS dest must be wave-uniform base; HW scatters lane*16.
__device__ __forceinline__ void gld_lds16(const float* g, float* lds_uniform) {
  __builtin_amdgcn_global_load_lds(
      (const __attribute__((address_space(1))) void*)g,
      (__attribute__((address_space(3))) void*)lds_uniform, 16, 0, 0);
}

__device__ __forceinline__ bf16x8 neg8(bf16x8 v) {
  union { bf16x8 b; u32x4 u; } x;
  x.b = v;
  x.u = x.u ^ 0x80008000u;  // flip bf16 sign bits (packed)
  return x.b;
}

// Read one A fragment (8 fp32 along k) from the granule-swizzled fp32 LDS tile
// and convert to bf16x8. Tile layout: slot(row, g') holds global granule
// g = g' ^ (row & 7); granule = 4 floats = 16 B.
__device__ __forceinline__ bf16x8 afrag(const float* ldsx, int r, int h4) {
  const int base = r * 8;
  const int sw = r & 7;
  const float4 a = *(const float4*)(ldsx + 4 * (base + ((2 * h4) ^ sw)));
  const float4 b = *(const float4*)(ldsx + 4 * (base + ((2 * h4 + 1) ^ sw)));
  bf16x8 f;
  f[0] = (__bf16)a.x; f[1] = (__bf16)a.y; f[2] = (__bf16)a.z; f[3] = (__bf16)a.w;
  f[4] = (__bf16)b.x; f[5] = (__bf16)b.y; f[6] = (__bf16)b.z; f[7] = (__bf16)b.w;
  return f;
}

__global__ __launch_bounds__(256, 2) void dft_cgemm_kernel(
    const float* __restrict__ xr, const float* __restrict__ xi,
    const float* __restrict__ wre, const float* __restrict__ wim,
    float* __restrict__ out) {
  __shared__ __align__(16) float lds_xr[BM * BK];    // 16 KB, granule-swizzled
  __shared__ __align__(16) float lds_xi[BM * BK];    // 16 KB
  __shared__ __align__(16) bf16_t lds_wr[BN * WSTRIDE];  // 10 KB, padded
  __shared__ __align__(16) bf16_t lds_wi[BN * WSTRIDE];  // 10 KB

  const int t = threadIdx.x;
  const int lane = t & 63;
  const int wv = t >> 6;          // wave 0..3
  const int m0 = blockIdx.y * BM;
  const int n0 = blockIdx.x * BN;

  // wave tile: 64x64; 2x2 wave grid over the 128x128 block tile
  const int wm = (wv >> 1) * 64;
  const int wn = (wv & 1) * 64;
  const int l16 = lane & 15;      // A row / B row (n) within 16-frag
  const int h4 = lane >> 4;       // k-half selector (0..3)

  // weight staging coords: 2 threads per h-row, 16 elems each
  const int wrow = t >> 1;
  const int wcol = (t & 1) * 16;

  f32x4 acc_re[4][4], acc_im[4][4];
#pragma unroll
  for (int i = 0; i < 4; ++i)
#pragma unroll
    for (int j = 0; j < 4; ++j) {
      acc_re[i][j] = (f32x4){0.f, 0.f, 0.f, 0.f};
      acc_im[i][j] = (f32x4){0.f, 0.f, 0.f, 0.f};
    }

  for (int k0 = 0; k0 < KDIM; k0 += BK) {
    // ---- stage x (fp32, async DMA, granule-swizzled addresses) ----
#pragma unroll
    for (int it = 0; it < 4; ++it) {
      const int S = it * 256 + t;        // granule slot 0..1023
      const int row = S >> 3;
      const int g = (S & 7) ^ (row & 7); // global granule for this slot
      const size_t goff = (size_t)(m0 + row) * KDIM + k0 + g * 4;
      float* dst_r = lds_xr + 4 * (it * 256 + wv * 64);  // wave-uniform base
      float* dst_i = lds_xi + 4 * (it * 256 + wv * 64);
      gld_lds16(xr + goff, dst_r);
      gld_lds16(xi + goff, dst_i);
    }
    // ---- stage weights fp32 -> bf16 (register path, padded LDS) ----
    {
      const float* gwr = wre + (size_t)(n0 + wrow) * KDIM + k0 + wcol;
      const float* gwi = wim + (size_t)(n0 + wrow) * KDIM + k0 + wcol;
      const float4 a0 = ((const float4*)gwr)[0];
      const float4 a1 = ((const float4*)gwr)[1];
      const float4 a2 = ((const float4*)gwr)[2];
      const float4 a3 = ((const float4*)gwr)[3];
      const float4 b0 = ((const float4*)gwi)[0];
      const float4 b1 = ((const float4*)gwi)[1];
      const float4 b2 = ((const float4*)gwi)[2];
      const float4 b3 = ((const float4*)gwi)[3];
      bf16x8 pr0, pr1, pi0, pi1;
      pr0[0]=(__bf16)a0.x; pr0[1]=(__bf16)a0.y; pr0[2]=(__bf16)a0.z; pr0[3]=(__bf16)a0.w;
      pr0[4]=(__bf16)a1.x; pr0[5]=(__bf16)a1.y; pr0[6]=(__bf16)a1.z; pr0[7]=(__bf16)a1.w;
      pr1[0]=(__bf16)a2.x; pr1[1]=(__bf16)a2.y; pr1[2]=(__bf16)a2.z; pr1[3]=(__bf16)a2.w;
      pr1[4]=(__bf16)a3.x; pr1[5]=(__bf16)a3.y; pr1[6]=(__bf16)a3.z; pr1[7]=(__bf16)a3.w;
      pi0[0]=(__bf16)b0.x; pi0[1]=(__bf16)b0.y; pi0[2]=(__bf16)b0.z; pi0[3]=(__bf16)b0.w;
      pi0[4]=(__bf16)b1.x; pi0[5]=(__bf16)b1.y; pi0[6]=(__bf16)b1.z; pi0[7]=(__bf16)b1.w;
      pi1[0]=(__bf16)b2.x; pi1[1]=(__bf16)b2.y; pi1[2]=(__bf16)b2.z; pi1[3]=(__bf16)b2.w;
      pi1[4]=(__bf16)b3.x; pi1[5]=(__bf16)b3.y; pi1[6]=(__bf16)b3.z; pi1[7]=(__bf16)b3.w;
      *(bf16x8*)(lds_wr + wrow * WSTRIDE + wcol)     = pr0;
      *(bf16x8*)(lds_wr + wrow * WSTRIDE + wcol + 8) = pr1;
      *(bf16x8*)(lds_wi + wrow * WSTRIDE + wcol)     = pi0;
      *(bf16x8*)(lds_wi + wrow * WSTRIDE + wcol + 8) = pi1;
    }
    __syncthreads();  // drains vmcnt (global_load_lds) + lgkmcnt (ds_write)

    // ---- fragments ----
    bf16x8 ar[4], ai[4], br[4], bi[4], nbi[4];
#pragma unroll
    for (int mi = 0; mi < 4; ++mi) {
      const int r = wm + mi * 16 + l16;
      ar[mi] = afrag(lds_xr, r, h4);
      ai[mi] = afrag(lds_xi, r, h4);
    }
#pragma unroll
    for (int ni = 0; ni < 4; ++ni) {
      const int r = wn + ni * 16 + l16;
      br[ni] = *(const bf16x8*)(lds_wr + r * WSTRIDE + h4 * 8);
      bi[ni] = *(const bf16x8*)(lds_wi + r * WSTRIDE + h4 * 8);
      nbi[ni] = neg8(bi[ni]);
    }
    // ---- 4 MFMA streams: re += xr*wr - xi*wi ; im += xr*wi + xi*wr ----
#pragma unroll
    for (int mi = 0; mi < 4; ++mi) {
#pragma unroll
      for (int ni = 0; ni < 4; ++ni) {
        acc_re[mi][ni] = __builtin_amdgcn_mfma_f32_16x16x32_bf16(ar[mi], br[ni], acc_re[mi][ni], 0, 0, 0);
        acc_im[mi][ni] = __builtin_amdgcn_mfma_f32_16x16x32_bf16(ar[mi], bi[ni], acc_im[mi][ni], 0, 0, 0);
        acc_re[mi][ni] = __builtin_amdgcn_mfma_f32_16x16x32_bf16(ai[mi], nbi[ni], acc_re[mi][ni], 0, 0, 0);
        acc_im[mi][ni] = __builtin_amdgcn_mfma_f32_16x16x32_bf16(ai[mi], br[ni], acc_im[mi][ni], 0, 0, 0);
      }
    }
    __syncthreads();  // protect LDS before next stage
  }

  // ---- epilogue: interleaved (re, im) float2 stores, coalesced in h ----
#pragma unroll
  for (int mi = 0; mi < 4; ++mi) {
#pragma unroll
    for (int r = 0; r < 4; ++r) {
      const int m = m0 + wm + mi * 16 + h4 * 4 + r;  // C/D: row = (lane>>4)*4 + reg
#pragma unroll
      for (int ni = 0; ni < 4; ++ni) {
        const int h = n0 + wn + ni * 16 + l16;       // C/D: col = lane & 15
        float2 v;
        v.x = acc_re[mi][ni][r];
        v.y = acc_im[mi][ni][r];
        *(float2*)(out + ((size_t)m * NDIM + h) * 2) = v;
      }
    }
  }
}

extern "C" void kernel_launch(void* const* d_in, const int* in_sizes, int n_in,
                              void* d_out, int out_size, void* d_ws, size_t ws_size,
                              hipStream_t stream) {
  const float* xr  = (const float*)d_in[0];
  const float* xi  = (const float*)d_in[1];
  const float* wre = (const float*)d_in[2];
  const float* wim = (const float*)d_in[3];
  float* out = (float*)d_out;

  const int M = in_sizes[0] / KDIM;  // 8*16*256 = 32768
  dim3 grid(NDIM / BN, M / BM);      // (4, 256)
  dim3 block(256);
  dft_cgemm_kernel<<<grid, block, 0, stream>>>(xr, xi, wre, wim, out);
}

// Round 2
// 291.534 us; speedup vs baseline: 1.0137x; 1.0137x over previous
//
#include <hip/hip_runtime.h>

typedef __bf16 bf16_t;
typedef __bf16 bf16x8 __attribute__((ext_vector_type(8)));
typedef float f32x4 __attribute__((ext_vector_type(4)));
typedef unsigned int u32x4 __attribute__((ext_vector_type(4)));

#define KDIM 512
#define NDIM 512
#define BM 128
#define BN 128
#define BK 32

// async 16B global->LDS. LDS dest must be wave-uniform base; HW scatters lane*16.
__device__ __forceinline__ void gld_lds16(const float* g, float* lds_uniform) {
  __builtin_amdgcn_global_load_lds(
      (const __attribute__((address_space(1))) void*)g,
      (__attribute__((address_space(3))) void*)lds_uniform, 16, 0, 0);
}

__device__ __forceinline__ bf16x8 neg8(bf16x8 v) {
  union { bf16x8 b; u32x4 u; } x;
  x.b = v;
  x.u = x.u ^ 0x80008000u;  // flip bf16 sign bits (packed)
  return x.b;
}

// Read one A fragment (8 fp32 along k) from the granule-swizzled fp32 LDS tile
// and convert to bf16x8. Tile layout: slot(row, g') holds global granule
// g = g' ^ (row & 7); granule = 4 floats = 16 B. 2-way bank alias only (free).
__device__ __forceinline__ bf16x8 afrag(const float* ldsx, int r, int h4) {
  const int base = r * 8;
  const int sw = r & 7;
  const float4 a = *(const float4*)(ldsx + 4 * (base + ((2 * h4) ^ sw)));
  const float4 b = *(const float4*)(ldsx + 4 * (base + ((2 * h4 + 1) ^ sw)));
  bf16x8 f;
  f[0] = (__bf16)a.x; f[1] = (__bf16)a.y; f[2] = (__bf16)a.z; f[3] = (__bf16)a.w;
  f[4] = (__bf16)b.x; f[5] = (__bf16)b.y; f[6] = (__bf16)b.z; f[7] = (__bf16)b.w;
  return f;
}

__device__ __forceinline__ bf16x8 pack8(float4 a, float4 b) {
  bf16x8 f;
  f[0] = (__bf16)a.x; f[1] = (__bf16)a.y; f[2] = (__bf16)a.z; f[3] = (__bf16)a.w;
  f[4] = (__bf16)b.x; f[5] = (__bf16)b.y; f[6] = (__bf16)b.z; f[7] = (__bf16)b.w;
  return f;
}

__global__ __launch_bounds__(256, 2) void dft_cgemm_kernel(
    const float* __restrict__ xr, const float* __restrict__ xi,
    const float* __restrict__ wre, const float* __restrict__ wim,
    float* __restrict__ out) {
  __shared__ __align__(16) float lds_xr[BM * BK];   // 16 KB, granule-swizzled fp32
  __shared__ __align__(16) float lds_xi[BM * BK];   // 16 KB
  // weights: bf16, FRAGMENT-ORDERED layout. 16B slot index for (row, g):
  //   slot = (row>>4)*64 + g*16 + (row&15)
  // frag read = wave-contiguous 1 KB (conflict-free canonical pattern).
  __shared__ __align__(16) bf16_t lds_wr[BN * BK];  // 8 KB
  __shared__ __align__(16) bf16_t lds_wi[BN * BK];  // 8 KB

  const int t = threadIdx.x;
  const int lane = t & 63;
  const int wv = t >> 6;          // wave 0..3

  // XCD-aware swizzle: xcd = b&7 owns m-tiles [32*xcd, 32*xcd+32) x all 4 n-tiles,
  // so each XCD's L2 fetches a given x-row range exactly once.
  const int b = blockIdx.x;                 // 0..1023
  const int xcd = b & 7;
  const int sidx = b >> 3;                  // 0..127
  const int m0 = (xcd * 32 + (sidx >> 2)) * BM;
  const int n0 = (sidx & 3) * BN;

  // wave tile: 64x64; 2x2 wave grid over the 128x128 block tile
  const int wm = (wv >> 1) * 64;
  const int wn = (wv & 1) * 64;
  const int l16 = lane & 15;      // A row / B row (n) within 16-frag
  const int h4 = lane >> 4;       // k-granule selector (0..3)

  // weight staging: thread t handles fragment-slots {t, 256+t} per tile.
  // slot = c*256 + t  <=>  row = (c*4 + wv)*16 + (t&15), g = (t>>4)&3
  const int wt15 = t & 15;
  const int wg = (t >> 4) & 3;

  f32x4 acc_re[4][4], acc_im[4][4];
#pragma unroll
  for (int i = 0; i < 4; ++i)
#pragma unroll
    for (int j = 0; j < 4; ++j) {
      acc_re[i][j] = (f32x4){0.f, 0.f, 0.f, 0.f};
      acc_im[i][j] = (f32x4){0.f, 0.f, 0.f, 0.f};
    }

  for (int k0 = 0; k0 < KDIM; k0 += BK) {
    // ---- stage x (fp32, async DMA, granule-swizzled addresses) ----
#pragma unroll
    for (int it = 0; it < 4; ++it) {
      const int S = it * 256 + t;        // granule slot 0..1023
      const int row = S >> 3;
      const int g = (S & 7) ^ (row & 7); // global granule for this slot
      const size_t goff = (size_t)(m0 + row) * KDIM + k0 + g * 4;
      float* dst_r = lds_xr + 4 * (it * 256 + wv * 64);  // wave-uniform base
      float* dst_i = lds_xi + 4 * (it * 256 + wv * 64);
      gld_lds16(xr + goff, dst_r);
      gld_lds16(xi + goff, dst_i);
    }
    // ---- stage weights fp32 -> bf16 into fragment-ordered LDS ----
#pragma unroll
    for (int c = 0; c < 2; ++c) {
      const int row = (c * 4 + wv) * 16 + wt15;
      const float* gr = wre + (size_t)(n0 + row) * KDIM + k0 + wg * 8;
      const float* gi = wim + (size_t)(n0 + row) * KDIM + k0 + wg * 8;
      const float4 r0 = ((const float4*)gr)[0];
      const float4 r1 = ((const float4*)gr)[1];
      const float4 i0 = ((const float4*)gi)[0];
      const float4 i1 = ((const float4*)gi)[1];
      const int slot = c * 256 + t;            // wave-contiguous write
      *(bf16x8*)(lds_wr + slot * 8) = pack8(r0, r1);
      *(bf16x8*)(lds_wi + slot * 8) = pack8(i0, i1);
    }
    __syncthreads();  // drains vmcnt (global_load_lds) + lgkmcnt (ds_write)

    // ---- fragments ----
    bf16x8 ar[4], ai[4], br[4], bi[4], nbi[4];
#pragma unroll
    for (int mi = 0; mi < 4; ++mi) {
      const int r = wm + mi * 16 + l16;
      ar[mi] = afrag(lds_xr, r, h4);
      ai[mi] = afrag(lds_xi, r, h4);
    }
#pragma unroll
    for (int ni = 0; ni < 4; ++ni) {
      const int slot = ((wn >> 4) + ni) * 64 + h4 * 16 + l16;
      br[ni] = *(const bf16x8*)(lds_wr + slot * 8);
      bi[ni] = *(const bf16x8*)(lds_wi + slot * 8);
      nbi[ni] = neg8(bi[ni]);
    }
    // ---- 4 MFMA streams: re += xr*wr - xi*wi ; im += xr*wi + xi*wr ----
#pragma unroll
    for (int mi = 0; mi < 4; ++mi) {
#pragma unroll
      for (int ni = 0; ni < 4; ++ni) {
        acc_re[mi][ni] = __builtin_amdgcn_mfma_f32_16x16x32_bf16(ar[mi], br[ni], acc_re[mi][ni], 0, 0, 0);
        acc_im[mi][ni] = __builtin_amdgcn_mfma_f32_16x16x32_bf16(ar[mi], bi[ni], acc_im[mi][ni], 0, 0, 0);
        acc_re[mi][ni] = __builtin_amdgcn_mfma_f32_16x16x32_bf16(ai[mi], nbi[ni], acc_re[mi][ni], 0, 0, 0);
        acc_im[mi][ni] = __builtin_amdgcn_mfma_f32_16x16x32_bf16(ai[mi], br[ni], acc_im[mi][ni], 0, 0, 0);
      }
    }
    __syncthreads();  // protect LDS before next stage
  }

  // ---- epilogue: interleaved (re, im) float2 stores, coalesced in h ----
#pragma unroll
  for (int mi = 0; mi < 4; ++mi) {
#pragma unroll
    for (int r = 0; r < 4; ++r) {
      const int m = m0 + wm + mi * 16 + h4 * 4 + r;  // C/D: row = (lane>>4)*4 + reg
#pragma unroll
      for (int ni = 0; ni < 4; ++ni) {
        const int h = n0 + wn + ni * 16 + l16;       // C/D: col = lane & 15
        float2 v;
        v.x = acc_re[mi][ni][r];
        v.y = acc_im[mi][ni][r];
        *(float2*)(out + ((size_t)m * NDIM + h) * 2) = v;
      }
    }
  }
}

extern "C" void kernel_launch(void* const* d_in, const int* in_sizes, int n_in,
                              void* d_out, int out_size, void* d_ws, size_t ws_size,
                              hipStream_t stream) {
  const float* xr  = (const float*)d_in[0];
  const float* xi  = (const float*)d_in[1];
  const float* wre = (const float*)d_in[2];
  const float* wim = (const float*)d_in[3];
  float* out = (float*)d_out;

  dim3 grid(1024);  // (m-tiles 256) x (n-tiles 4), XCD-swizzled inside kernel
  dim3 block(256);
  dft_cgemm_kernel<<<grid, block, 0, stream>>>(xr, xi, wre, wim, out);
}